// Round 14
// baseline (127.932 us; speedup 1.0000x reference)
//
#include <hip/hip_runtime.h>
#include <stdint.h>

#define AQ_MAX 15.0f
#define BN_EPS 1e-5f

// ---------------------------------------------------------------------------
// Merged prep: per-output-channel int4 symmetric weight fake-quant + BN fold.
// P layout (floats): wq1[32*28]@0 wq2[288]@896 wq3[1536]@1184 wq4[432]@2720
//   wq5[3072]@3152 | inv1@6224 beta1@6256 inv2@6288 beta2@6320 inv3@6352
//   beta3@6400 inv4@6448 beta4@6496 inv5@6544 beta5@6608 (end 6672)
// ---------------------------------------------------------------------------
__global__ __launch_bounds__(64) void prep_all(
    const float* __restrict__ wA, const float* __restrict__ gA,
    const float* __restrict__ bA, const float* __restrict__ mA,
    const float* __restrict__ vA,
    const float* __restrict__ wB, const float* __restrict__ gB,
    const float* __restrict__ bB, const float* __restrict__ mB,
    const float* __restrict__ vB,
    const float* __restrict__ wC, const float* __restrict__ gC,
    const float* __restrict__ bC, const float* __restrict__ mC,
    const float* __restrict__ vC,
    const float* __restrict__ wD, const float* __restrict__ gD,
    const float* __restrict__ bD, const float* __restrict__ mD,
    const float* __restrict__ vD,
    const float* __restrict__ wE, const float* __restrict__ gE,
    const float* __restrict__ bE, const float* __restrict__ mE,
    const float* __restrict__ vE,
    float* __restrict__ P) {
  int blk = blockIdx.x, t = threadIdx.x;
  const float *w, *g, *b, *m, *v;
  float *wq, *inv, *beta;
  int K, KP, c;
  if (blk < 32) {
    c = blk; w = wA; g = gA; b = bA; m = mA; v = vA; K = 27; KP = 28;
    wq = P + 0; inv = P + 6224; beta = P + 6256;
  } else if (blk < 64) {
    c = blk - 32; w = wB; g = gB; b = bB; m = mB; v = vB; K = 9; KP = 9;
    wq = P + 896; inv = P + 6288; beta = P + 6320;
  } else if (blk < 112) {
    c = blk - 64; w = wC; g = gC; b = bC; m = mC; v = vC; K = 32; KP = 32;
    wq = P + 1184; inv = P + 6352; beta = P + 6400;
  } else if (blk < 160) {
    c = blk - 112; w = wD; g = gD; b = bD; m = mD; v = vD; K = 9; KP = 9;
    wq = P + 2720; inv = P + 6448; beta = P + 6496;
  } else {
    c = blk - 160; w = wE; g = gE; b = bE; m = mE; v = vE; K = 48; KP = 48;
    wq = P + 3152; inv = P + 6544; beta = P + 6608;
  }
  const float* wc = w + (size_t)c * K;
  float a = (t < K) ? fabsf(wc[t]) : 0.0f;
#pragma unroll
  for (int off = 32; off >= 1; off >>= 1) a = fmaxf(a, __shfl_xor(a, off));
  float s = fmaxf(a / 7.0f, 1e-8f);
  if (t < K) {
    float q = rintf(wc[t] / s);  // round half-to-even, same as jnp.round
    q = fminf(7.0f, fmaxf(-7.0f, q));
    wq[(size_t)c * KP + t] = q * s;
  } else if (t < KP) {
    wq[(size_t)c * KP + t] = 0.0f;
  }
  if (t == 0) {
    float iv = g[c] / sqrtf(v[c] + BN_EPS);
    inv[c] = iv;
    beta[c] = b[c] - m[c] * iv;
  }
}

// ---------------------------------------------------------------------------
// Stage 1 v8: conv 3x3 s2 p0, 3->32, fp32 -> uint4 codes [8,32,255,512(pad)].
// Persistent 4-px threads with A/B tap ping-pong: LOAD(next px) precedes
// COMPUTE(cur px) in program order, so each ~2900-cyc oc-loop covers the next
// ~900-cyc HBM tap latency. Round-13 counters: 27us VALU + 21us exposed VMEM
// stall — TLP (generations) didn't hide it; ILP across pixels should.
// Thread = (n, oyb in [0,64), gx); oy = oyb + {0,64,128,192} (192-iter valid
// iff oyb<63, covering all 255 rows exactly once).
// ---------------------------------------------------------------------------
__global__ __launch_bounds__(256) void stage1_kernel(
    const float* __restrict__ x, const float* __restrict__ P,
    const float* __restrict__ s1p, uint8_t* __restrict__ out) {
  int tid = blockIdx.x * 256 + threadIdx.x;  // 8*64*512 = 262,144 threads
  int gx = tid & 511;                        // 1 px/iter (col 511 = dead pad)
  int t2 = tid >> 9;
  int oyb = t2 & 63;
  int n = t2 >> 6;
  float s1 = *s1p;
  int ix0 = gx * 2;
  bool tailok = (ix0 + 2) < 1024;  // gx=511 pad px: tap 2 would be OOB
  const float* xn = x + (size_t)n * 3 * 512 * 1024;

  auto LOAD = [&](float r[9][3], int oy) {
    int iy = 2 * oy;
#pragma unroll
    for (int ic = 0; ic < 3; ic++)
#pragma unroll
      for (int kh = 0; kh < 3; kh++) {
        const float* bp = xn + ((size_t)ic * 512 + iy + kh) * 1024 + ix0;
        float2 f = *(const float2*)bp;  // 8B-aligned (ix0 even)
        int s = ic * 3 + kh;
        r[s][0] = f.x; r[s][1] = f.y;
        r[s][2] = tailok ? bp[2] : 0.0f;
      }
  };
  auto COMPUTE = [&](const float r[9][3], int oy) {
    size_t obase = (((size_t)n * 32) * 255 + oy) * 512 + gx;
#pragma unroll 2
    for (int oc = 0; oc < 32; oc++) {
      const float* wp = P + oc * 28;  // wave-uniform -> s_load chain
      float w[27];
#pragma unroll
      for (int j = 0; j < 27; j++) w[j] = wp[j];
      float a0 = 0.0f;
#pragma unroll
      for (int s = 0; s < 9; s++) {
#pragma unroll
        for (int kw = 0; kw < 3; kw++)
          a0 = fmaf(r[s][kw], w[s * 3 + kw], a0);
      }
      float iv = P[6224 + oc], bt = P[6256 + oc];
      float y0 = fmaf(a0, iv, bt);
      uint32_t q0 = (uint32_t)fminf(AQ_MAX, fmaxf(0.0f, rintf(y0 / s1)));
      out[obase + (size_t)oc * (255 * 512)] = (uint8_t)q0;
    }
  };

  float rA[9][3], rB[9][3];
  bool last = oyb < 63;  // oyb+192 < 255
  LOAD(rA, oyb);
  LOAD(rB, oyb + 64);      // in flight during COMPUTE(rA)
  COMPUTE(rA, oyb);
  LOAD(rA, oyb + 128);     // in flight during COMPUTE(rB)
  COMPUTE(rB, oyb + 64);
  if (last) LOAD(rB, oyb + 192);  // in flight during COMPUTE(rA)
  COMPUTE(rA, oyb + 128);
  if (last) COMPUTE(rB, oyb + 192);
}

// ---------------------------------------------------------------------------
// Depthwise 3x3 s2 p1, codes in -> codes out. 4 output px/thread. (unchanged)
// ---------------------------------------------------------------------------
template <int C, int IH, int IWL, int IWP, int OH, int OW>
__global__ __launch_bounds__(256) void dw_kernel(
    const uint8_t* __restrict__ in, const float* __restrict__ wq,
    const float* __restrict__ inv, const float* __restrict__ beta,
    const float* __restrict__ sin_p, const float* __restrict__ sout_p,
    uint8_t* __restrict__ out) {
  constexpr int GX = OW / 4;
  int tid = blockIdx.x * 256 + threadIdx.x;
  int oxg = tid % GX;
  int t2 = tid / GX;
  int oy = t2 % OH;
  int t3 = t2 / OH;
  int c = __builtin_amdgcn_readfirstlane(t3 % C);
  int n = __builtin_amdgcn_readfirstlane(t3 / C);
  float s_in = *sin_p, s_out = *sout_p;
  const float* wc = wq + c * 9;  // uniform -> s_load
  float w[9];
#pragma unroll
  for (int j = 0; j < 9; j++) w[j] = wc[j];
  float iv = inv[c], bt = beta[c];
  int c0 = oxg * 8;
  const uint8_t* chan = in + ((size_t)(n * C + c)) * IH * IWP;
  float xr[3][9];
#pragma unroll
  for (int kh = 0; kh < 3; kh++) {
    int iy = 2 * oy + kh - 1;
    if (iy >= 0 && iy < IH) {
      const uint8_t* rp = chan + (size_t)iy * IWP;
      uint2 u = *(const uint2*)(rp + c0);
      xr[kh][0] = (oxg > 0) ? (float)rp[c0 - 1] : 0.0f;
#pragma unroll
      for (int j = 0; j < 4; j++) xr[kh][1 + j] = (float)((u.x >> (8 * j)) & 255u);
#pragma unroll
      for (int j = 0; j < 4; j++) xr[kh][5 + j] = (float)((u.y >> (8 * j)) & 255u);
      if (IWL < IWP && oxg == GX - 1) xr[kh][8] = 0.0f;
    } else {
#pragma unroll
      for (int j = 0; j < 9; j++) xr[kh][j] = 0.0f;
    }
  }
#pragma unroll
  for (int kh = 0; kh < 3; kh++)
#pragma unroll
    for (int j = 0; j < 9; j++) xr[kh][j] *= s_in;
  float acc[4] = {0, 0, 0, 0};
#pragma unroll
  for (int kh = 0; kh < 3; kh++)
#pragma unroll
    for (int kw = 0; kw < 3; kw++) {
      float wv = w[kh * 3 + kw];
#pragma unroll
      for (int p = 0; p < 4; p++) acc[p] = fmaf(xr[kh][2 * p + kw], wv, acc[p]);
    }
  uint32_t pack = 0;
#pragma unroll
  for (int p = 0; p < 4; p++) {
    float y = fmaf(acc[p], iv, bt);
    float q = fminf(AQ_MAX, fmaxf(0.0f, rintf(y / s_out)));
    pack |= ((uint32_t)q) << (8 * p);
  }
  *(uint32_t*)(out + ((size_t)(n * C + c) * OH + oy) * OW + c0 / 2) = pack;
}

// ---------------------------------------------------------------------------
// Pointwise 1x1: 1 px/thread, oc-chunked (weights wave-uniform s_loads).
// ROT=true adds the rotated weight prefetch. FINAL writes fp32. (unchanged)
// ---------------------------------------------------------------------------
template <int IC, int OC, int CHUNK, int HW, bool FINAL, bool ROT>
__global__ __launch_bounds__(256) void pw_kernel(
    const uint8_t* __restrict__ in, const float* __restrict__ Pw,
    const float* __restrict__ Pinv, const float* __restrict__ Pbeta,
    const float* __restrict__ sin_p, const float* __restrict__ sout_p,
    void* __restrict__ outv) {
  constexpr int NCH = OC / CHUNK;
  int tid = blockIdx.x * 256 + threadIdx.x;  // 8 * NCH * HW threads
  int px = tid % HW;
  int rest = tid / HW;
  int chunk = __builtin_amdgcn_readfirstlane(rest % NCH);
  int n = __builtin_amdgcn_readfirstlane(rest / NCH);
  float s_in = *sin_p, s_out = *sout_p;
  const uint8_t* ib = in + (size_t)n * IC * HW + px;
  float xa[IC];
#pragma unroll
  for (int ic = 0; ic < IC; ic++)
    xa[ic] = (float)ib[(size_t)ic * HW] * s_in;
  int oc0 = chunk * CHUNK;
  if (ROT) {
    float wcur[IC], wnxt[IC], ivc, btc, ivn, btn;
#pragma unroll
    for (int j = 0; j < IC; j++) wcur[j] = Pw[(size_t)oc0 * IC + j];
    ivc = Pinv[oc0]; btc = Pbeta[oc0];
#pragma unroll
    for (int k = 0; k < CHUNK; k++) {
      int oc = oc0 + k;
      if (k < CHUNK - 1) {
#pragma unroll
        for (int j = 0; j < IC; j++) wnxt[j] = Pw[(size_t)(oc + 1) * IC + j];
        ivn = Pinv[oc + 1]; btn = Pbeta[oc + 1];
      }
      float a0 = 0;
#pragma unroll
      for (int ic = 0; ic < IC; ic++) a0 = fmaf(xa[ic], wcur[ic], a0);
      float y0 = fmaf(a0, ivc, btc);
      float q0 = fminf(AQ_MAX, fmaxf(0.0f, rintf(y0 / s_out)));
      if (FINAL) {
        ((float*)outv)[((size_t)n * OC + oc) * HW + px] = q0 * s_out;
      } else {
        ((uint8_t*)outv)[((size_t)n * OC + oc) * HW + px] = (uint8_t)q0;
      }
      if (k < CHUNK - 1) {
#pragma unroll
        for (int j = 0; j < IC; j++) wcur[j] = wnxt[j];
        ivc = ivn; btc = btn;
      }
    }
  } else {
#pragma unroll 2
    for (int oc = oc0; oc < oc0 + CHUNK; oc++) {
      const float* wp = Pw + (size_t)oc * IC;  // uniform -> s_load
      float w[IC];
#pragma unroll
      for (int ic = 0; ic < IC; ic++) w[ic] = wp[ic];
      float a0 = 0;
#pragma unroll
      for (int ic = 0; ic < IC; ic++) a0 = fmaf(xa[ic], w[ic], a0);
      float iv = Pinv[oc], bt = Pbeta[oc];
      float y0 = fmaf(a0, iv, bt);
      float q0 = fminf(AQ_MAX, fmaxf(0.0f, rintf(y0 / s_out)));
      if (FINAL) {
        ((float*)outv)[((size_t)n * OC + oc) * HW + px] = q0 * s_out;
      } else {
        ((uint8_t*)outv)[((size_t)n * OC + oc) * HW + px] = (uint8_t)q0;
      }
    }
  }
}

extern "C" void kernel_launch(void* const* d_in, const int* in_sizes, int n_in,
                              void* d_out, int out_size, void* d_ws, size_t ws_size,
                              hipStream_t stream) {
  const float* x    = (const float*)d_in[0];
  const float* w1   = (const float*)d_in[1];
  const float* g1   = (const float*)d_in[2];
  const float* b1   = (const float*)d_in[3];
  const float* m1   = (const float*)d_in[4];
  const float* v1   = (const float*)d_in[5];
  const float* s1   = (const float*)d_in[6];
  const float* wdw1 = (const float*)d_in[7];
  const float* g2   = (const float*)d_in[8];
  const float* b2   = (const float*)d_in[9];
  const float* m2   = (const float*)d_in[10];
  const float* v2   = (const float*)d_in[11];
  const float* s2   = (const float*)d_in[12];
  const float* wpw1 = (const float*)d_in[13];
  const float* g3   = (const float*)d_in[14];
  const float* b3   = (const float*)d_in[15];
  const float* m3   = (const float*)d_in[16];
  const float* v3   = (const float*)d_in[17];
  const float* s3   = (const float*)d_in[18];
  const float* wdw2 = (const float*)d_in[19];
  const float* g4   = (const float*)d_in[20];
  const float* b4   = (const float*)d_in[21];
  const float* m4   = (const float*)d_in[22];
  const float* v4   = (const float*)d_in[23];
  const float* s4   = (const float*)d_in[24];
  const float* wpw2 = (const float*)d_in[25];
  const float* g5   = (const float*)d_in[26];
  const float* b5   = (const float*)d_in[27];
  const float* m5   = (const float*)d_in[28];
  const float* v5   = (const float*)d_in[29];
  const float* s5   = (const float*)d_in[30];

  float* P = (float*)d_ws;
  float* wq2  = P + 896;
  float* wq3  = P + 1184;
  float* wq4  = P + 2720;
  float* wq5  = P + 3152;
  float* inv2 = P + 6288, *beta2 = P + 6320;
  float* inv3 = P + 6352, *beta3 = P + 6400;
  float* inv4 = P + 6448, *beta4 = P + 6496;
  float* inv5 = P + 6544, *beta5 = P + 6608;

  uint8_t* ws8 = (uint8_t*)d_ws;
  uint8_t* x1 = ws8 + 32768;            // [8,32,255,512] codes: 33,423,360 B
  uint8_t* x2 = x1 + 33423360;          // [8,32,128,256]:  8,388,608 B
  uint8_t* x3 = x2 + 8388608;           // [8,48,128,256]: 12,582,912 B
  uint8_t* x4 = ws8 + 32768;            // [8,48,64,128]: aliases x1 (dead)

  prep_all<<<224, 64, 0, stream>>>(w1, g1, b1, m1, v1,
                                   wdw1, g2, b2, m2, v2,
                                   wpw1, g3, b3, m3, v3,
                                   wdw2, g4, b4, m4, v4,
                                   wpw2, g5, b5, m5, v5, P);

  // Stage 1: 262,144 persistent threads, 4 px each (A/B pipelined)
  stage1_kernel<<<1024, 256, 0, stream>>>(x, P, s1, x1);
  // dw1: 32ch, 255x511(512) -> 128x256
  dw_kernel<32, 255, 511, 512, 128, 256>
      <<<8192, 256, 0, stream>>>(x1, wq2, inv2, beta2, s1, s2, x2);
  // pw1: 32->48 @128x256, single chunk, 1 px/thread, rotated prefetch
  pw_kernel<32, 48, 48, 32768, false, true>
      <<<1024, 256, 0, stream>>>(x2, wq3, inv3, beta3, s2, s3, x3);
  // dw2: 48ch, 128x256 -> 64x128
  dw_kernel<48, 128, 256, 256, 64, 128>
      <<<3072, 256, 0, stream>>>(x3, wq4, inv4, beta4, s3, s4, x4);
  // pw2: 48->64 @64x128 -> fp32, chunk 16 (4 chunks), 1 px/thread
  pw_kernel<48, 64, 16, 8192, true, false>
      <<<1024, 256, 0, stream>>>(x4, wq5, inv5, beta5, s4, s5, (float*)d_out);
}

// Round 15
// 113.243 us; speedup vs baseline: 1.1297x; 1.1297x over previous
//
#include <hip/hip_runtime.h>
#include <stdint.h>

#define AQ_MAX 15.0f
#define BN_EPS 1e-5f

// ---------------------------------------------------------------------------
// Merged prep: per-output-channel int4 symmetric weight fake-quant + BN fold.
// P layout (floats): wq1[32*28]@0 wq2[288]@896 wq3[1536]@1184 wq4[432]@2720
//   wq5[3072]@3152 | inv1@6224 beta1@6256 inv2@6288 beta2@6320 inv3@6352
//   beta3@6400 inv4@6448 beta4@6496 inv5@6544 beta5@6608 (end 6672)
// ---------------------------------------------------------------------------
__global__ __launch_bounds__(64) void prep_all(
    const float* __restrict__ wA, const float* __restrict__ gA,
    const float* __restrict__ bA, const float* __restrict__ mA,
    const float* __restrict__ vA,
    const float* __restrict__ wB, const float* __restrict__ gB,
    const float* __restrict__ bB, const float* __restrict__ mB,
    const float* __restrict__ vB,
    const float* __restrict__ wC, const float* __restrict__ gC,
    const float* __restrict__ bC, const float* __restrict__ mC,
    const float* __restrict__ vC,
    const float* __restrict__ wD, const float* __restrict__ gD,
    const float* __restrict__ bD, const float* __restrict__ mD,
    const float* __restrict__ vD,
    const float* __restrict__ wE, const float* __restrict__ gE,
    const float* __restrict__ bE, const float* __restrict__ mE,
    const float* __restrict__ vE,
    float* __restrict__ P) {
  int blk = blockIdx.x, t = threadIdx.x;
  const float *w, *g, *b, *m, *v;
  float *wq, *inv, *beta;
  int K, KP, c;
  if (blk < 32) {
    c = blk; w = wA; g = gA; b = bA; m = mA; v = vA; K = 27; KP = 28;
    wq = P + 0; inv = P + 6224; beta = P + 6256;
  } else if (blk < 64) {
    c = blk - 32; w = wB; g = gB; b = bB; m = mB; v = vB; K = 9; KP = 9;
    wq = P + 896; inv = P + 6288; beta = P + 6320;
  } else if (blk < 112) {
    c = blk - 64; w = wC; g = gC; b = bC; m = mC; v = vC; K = 32; KP = 32;
    wq = P + 1184; inv = P + 6352; beta = P + 6400;
  } else if (blk < 160) {
    c = blk - 112; w = wD; g = gD; b = bD; m = mD; v = vD; K = 9; KP = 9;
    wq = P + 2720; inv = P + 6448; beta = P + 6496;
  } else {
    c = blk - 160; w = wE; g = gE; b = bE; m = mE; v = vE; K = 48; KP = 48;
    wq = P + 3152; inv = P + 6544; beta = P + 6608;
  }
  const float* wc = w + (size_t)c * K;
  float a = (t < K) ? fabsf(wc[t]) : 0.0f;
#pragma unroll
  for (int off = 32; off >= 1; off >>= 1) a = fmaxf(a, __shfl_xor(a, off));
  float s = fmaxf(a / 7.0f, 1e-8f);
  if (t < K) {
    float q = rintf(wc[t] / s);  // round half-to-even, same as jnp.round
    q = fminf(7.0f, fmaxf(-7.0f, q));
    wq[(size_t)c * KP + t] = q * s;
  } else if (t < KP) {
    wq[(size_t)c * KP + t] = 0.0f;
  }
  if (t == 0) {
    float iv = g[c] / sqrtf(v[c] + BN_EPS);
    inv[c] = iv;
    beta[c] = b[c] - m[c] * iv;
  }
}

// ---------------------------------------------------------------------------
// Stage 1 v9: v4 structure (best measured: 2 px/thread, zero LDS, SGPR
// weights) + NIBBLE-PACKED output: codes are 4-bit, so the 2 px pack into ONE
// byte -> x1 halves to 16.7 MB (layout [8][32][255][256B]). Every stage1
// variant ran at ~1.5 TB/s duty cycle — time tracks bytes, so cut bytes.
// ---------------------------------------------------------------------------
__global__ __launch_bounds__(256) void stage1_kernel(
    const float* __restrict__ x, const float* __restrict__ P,
    const float* __restrict__ s1p, uint8_t* __restrict__ out) {
  int tid = blockIdx.x * 256 + threadIdx.x;  // 8*255*256 = 522,240 threads
  int gx = tid & 255;                        // 2-px group along ox
  int t2 = tid >> 8;
  int oy = t2 % 255;
  int n = t2 / 255;
  float s1 = *s1p;
  int ix0 = gx * 4, iy = 2 * oy;
  bool tailok = (ix0 + 4) < 1024;  // tap 4 only feeds the dead pad px at gx=255
  float r[9][5];
#pragma unroll
  for (int ic = 0; ic < 3; ic++)
#pragma unroll
    for (int kh = 0; kh < 3; kh++) {
      const float* bp = x + (((size_t)(n * 3 + ic)) * 512 + (iy + kh)) * 1024 + ix0;
      float4 f = *(const float4*)bp;
      int s = ic * 3 + kh;
      r[s][0] = f.x; r[s][1] = f.y; r[s][2] = f.z; r[s][3] = f.w;
      r[s][4] = tailok ? bp[4] : 0.0f;
    }
  size_t obase = (((size_t)n * 32) * 255 + oy) * 256 + gx;  // byte index
#pragma unroll 2
  for (int oc = 0; oc < 32; oc++) {
    const float* wp = P + oc * 28;  // wave-uniform -> s_load_dwordx4 chain
    float w[27];
#pragma unroll
    for (int j = 0; j < 27; j++) w[j] = wp[j];
    float a0 = 0.0f, a1 = 0.0f;
#pragma unroll
    for (int s = 0; s < 9; s++) {
#pragma unroll
      for (int kw = 0; kw < 3; kw++) {
        float wv = w[s * 3 + kw];
        a0 = fmaf(r[s][0 + kw], wv, a0);
        a1 = fmaf(r[s][2 + kw], wv, a1);
      }
    }
    float iv = P[6224 + oc], bt = P[6256 + oc];
    float y0 = fmaf(a0, iv, bt), y1 = fmaf(a1, iv, bt);
    uint32_t q0 = (uint32_t)fminf(AQ_MAX, fmaxf(0.0f, rintf(y0 / s1)));
    uint32_t q1 = (uint32_t)fminf(AQ_MAX, fmaxf(0.0f, rintf(y1 / s1)));
    out[obase + (size_t)oc * (255 * 256)] = (uint8_t)(q0 | (q1 << 4));
  }
}

// ---------------------------------------------------------------------------
// Depthwise 3x3 s2 p1, codes in -> codes out. 4 output px/thread.
// NIB=true: input is nibble-packed, IWP = BYTES per row (px = 2*IWP phys);
// unpack 8 px from one uint32. NIB=false: byte codes, IWP = px per row.
// Codes are identical integers either way -> dequant math bit-exact.
// ---------------------------------------------------------------------------
template <int C, int IH, int IWL, int IWP, int OH, int OW, bool NIB>
__global__ __launch_bounds__(256) void dw_kernel(
    const uint8_t* __restrict__ in, const float* __restrict__ wq,
    const float* __restrict__ inv, const float* __restrict__ beta,
    const float* __restrict__ sin_p, const float* __restrict__ sout_p,
    uint8_t* __restrict__ out) {
  constexpr int GX = OW / 4;
  constexpr bool HASPAD = NIB ? (IWL < 2 * IWP) : (IWL < IWP);
  int tid = blockIdx.x * 256 + threadIdx.x;
  int oxg = tid % GX;
  int t2 = tid / GX;
  int oy = t2 % OH;
  int t3 = t2 / OH;
  int c = __builtin_amdgcn_readfirstlane(t3 % C);
  int n = __builtin_amdgcn_readfirstlane(t3 / C);
  float s_in = *sin_p, s_out = *sout_p;
  const float* wc = wq + c * 9;  // uniform -> s_load
  float w[9];
#pragma unroll
  for (int j = 0; j < 9; j++) w[j] = wc[j];
  float iv = inv[c], bt = beta[c];
  int c0 = oxg * 8;  // first input px of this group
  const uint8_t* chan = in + ((size_t)(n * C + c)) * IH * IWP;
  float xr[3][9];
#pragma unroll
  for (int kh = 0; kh < 3; kh++) {
    int iy = 2 * oy + kh - 1;
    if (iy >= 0 && iy < IH) {
      const uint8_t* rp = chan + (size_t)iy * IWP;
      if (NIB) {
        uint32_t u = *(const uint32_t*)(rp + c0 / 2);  // px c0..c0+7
        xr[kh][0] = (oxg > 0) ? (float)((rp[c0 / 2 - 1] >> 4) & 15u) : 0.0f;
#pragma unroll
        for (int j = 0; j < 8; j++)
          xr[kh][1 + j] = (float)((u >> (4 * j)) & 15u);
      } else {
        uint2 u = *(const uint2*)(rp + c0);
        xr[kh][0] = (oxg > 0) ? (float)rp[c0 - 1] : 0.0f;
#pragma unroll
        for (int j = 0; j < 4; j++) xr[kh][1 + j] = (float)((u.x >> (8 * j)) & 255u);
#pragma unroll
        for (int j = 0; j < 4; j++) xr[kh][5 + j] = (float)((u.y >> (8 * j)) & 255u);
      }
      if (HASPAD && oxg == GX - 1) xr[kh][8] = 0.0f;  // pad col beyond IWL
    } else {
#pragma unroll
      for (int j = 0; j < 9; j++) xr[kh][j] = 0.0f;
    }
  }
#pragma unroll
  for (int kh = 0; kh < 3; kh++)
#pragma unroll
    for (int j = 0; j < 9; j++) xr[kh][j] *= s_in;
  float acc[4] = {0, 0, 0, 0};
#pragma unroll
  for (int kh = 0; kh < 3; kh++)
#pragma unroll
    for (int kw = 0; kw < 3; kw++) {
      float wv = w[kh * 3 + kw];
#pragma unroll
      for (int p = 0; p < 4; p++) acc[p] = fmaf(xr[kh][2 * p + kw], wv, acc[p]);
    }
  uint32_t pack = 0;
#pragma unroll
  for (int p = 0; p < 4; p++) {
    float y = fmaf(acc[p], iv, bt);
    float q = fminf(AQ_MAX, fmaxf(0.0f, rintf(y / s_out)));
    pack |= ((uint32_t)q) << (8 * p);
  }
  *(uint32_t*)(out + ((size_t)(n * C + c) * OH + oy) * OW + c0 / 2) = pack;
}

// ---------------------------------------------------------------------------
// Pointwise 1x1: 1 px/thread, oc-chunked (weights wave-uniform s_loads).
// ROT=true adds the rotated weight prefetch. FINAL writes fp32. (round 13)
// ---------------------------------------------------------------------------
template <int IC, int OC, int CHUNK, int HW, bool FINAL, bool ROT>
__global__ __launch_bounds__(256) void pw_kernel(
    const uint8_t* __restrict__ in, const float* __restrict__ Pw,
    const float* __restrict__ Pinv, const float* __restrict__ Pbeta,
    const float* __restrict__ sin_p, const float* __restrict__ sout_p,
    void* __restrict__ outv) {
  constexpr int NCH = OC / CHUNK;
  int tid = blockIdx.x * 256 + threadIdx.x;  // 8 * NCH * HW threads
  int px = tid % HW;
  int rest = tid / HW;
  int chunk = __builtin_amdgcn_readfirstlane(rest % NCH);
  int n = __builtin_amdgcn_readfirstlane(rest / NCH);
  float s_in = *sin_p, s_out = *sout_p;
  const uint8_t* ib = in + (size_t)n * IC * HW + px;
  float xa[IC];
#pragma unroll
  for (int ic = 0; ic < IC; ic++)
    xa[ic] = (float)ib[(size_t)ic * HW] * s_in;
  int oc0 = chunk * CHUNK;
  if (ROT) {
    float wcur[IC], wnxt[IC], ivc, btc, ivn, btn;
#pragma unroll
    for (int j = 0; j < IC; j++) wcur[j] = Pw[(size_t)oc0 * IC + j];
    ivc = Pinv[oc0]; btc = Pbeta[oc0];
#pragma unroll
    for (int k = 0; k < CHUNK; k++) {
      int oc = oc0 + k;
      if (k < CHUNK - 1) {
#pragma unroll
        for (int j = 0; j < IC; j++) wnxt[j] = Pw[(size_t)(oc + 1) * IC + j];
        ivn = Pinv[oc + 1]; btn = Pbeta[oc + 1];
      }
      float a0 = 0;
#pragma unroll
      for (int ic = 0; ic < IC; ic++) a0 = fmaf(xa[ic], wcur[ic], a0);
      float y0 = fmaf(a0, ivc, btc);
      float q0 = fminf(AQ_MAX, fmaxf(0.0f, rintf(y0 / s_out)));
      if (FINAL) {
        ((float*)outv)[((size_t)n * OC + oc) * HW + px] = q0 * s_out;
      } else {
        ((uint8_t*)outv)[((size_t)n * OC + oc) * HW + px] = (uint8_t)q0;
      }
      if (k < CHUNK - 1) {
#pragma unroll
        for (int j = 0; j < IC; j++) wcur[j] = wnxt[j];
        ivc = ivn; btc = btn;
      }
    }
  } else {
#pragma unroll 2
    for (int oc = oc0; oc < oc0 + CHUNK; oc++) {
      const float* wp = Pw + (size_t)oc * IC;  // uniform -> s_load
      float w[IC];
#pragma unroll
      for (int ic = 0; ic < IC; ic++) w[ic] = wp[ic];
      float a0 = 0;
#pragma unroll
      for (int ic = 0; ic < IC; ic++) a0 = fmaf(xa[ic], w[ic], a0);
      float iv = Pinv[oc], bt = Pbeta[oc];
      float y0 = fmaf(a0, iv, bt);
      float q0 = fminf(AQ_MAX, fmaxf(0.0f, rintf(y0 / s_out)));
      if (FINAL) {
        ((float*)outv)[((size_t)n * OC + oc) * HW + px] = q0 * s_out;
      } else {
        ((uint8_t*)outv)[((size_t)n * OC + oc) * HW + px] = (uint8_t)q0;
      }
    }
  }
}

extern "C" void kernel_launch(void* const* d_in, const int* in_sizes, int n_in,
                              void* d_out, int out_size, void* d_ws, size_t ws_size,
                              hipStream_t stream) {
  const float* x    = (const float*)d_in[0];
  const float* w1   = (const float*)d_in[1];
  const float* g1   = (const float*)d_in[2];
  const float* b1   = (const float*)d_in[3];
  const float* m1   = (const float*)d_in[4];
  const float* v1   = (const float*)d_in[5];
  const float* s1   = (const float*)d_in[6];
  const float* wdw1 = (const float*)d_in[7];
  const float* g2   = (const float*)d_in[8];
  const float* b2   = (const float*)d_in[9];
  const float* m2   = (const float*)d_in[10];
  const float* v2   = (const float*)d_in[11];
  const float* s2   = (const float*)d_in[12];
  const float* wpw1 = (const float*)d_in[13];
  const float* g3   = (const float*)d_in[14];
  const float* b3   = (const float*)d_in[15];
  const float* m3   = (const float*)d_in[16];
  const float* v3   = (const float*)d_in[17];
  const float* s3   = (const float*)d_in[18];
  const float* wdw2 = (const float*)d_in[19];
  const float* g4   = (const float*)d_in[20];
  const float* b4   = (const float*)d_in[21];
  const float* m4   = (const float*)d_in[22];
  const float* v4   = (const float*)d_in[23];
  const float* s4   = (const float*)d_in[24];
  const float* wpw2 = (const float*)d_in[25];
  const float* g5   = (const float*)d_in[26];
  const float* b5   = (const float*)d_in[27];
  const float* m5   = (const float*)d_in[28];
  const float* v5   = (const float*)d_in[29];
  const float* s5   = (const float*)d_in[30];

  float* P = (float*)d_ws;
  float* wq2  = P + 896;
  float* wq3  = P + 1184;
  float* wq4  = P + 2720;
  float* wq5  = P + 3152;
  float* inv2 = P + 6288, *beta2 = P + 6320;
  float* inv3 = P + 6352, *beta3 = P + 6400;
  float* inv4 = P + 6448, *beta4 = P + 6496;
  float* inv5 = P + 6544, *beta5 = P + 6608;

  uint8_t* ws8 = (uint8_t*)d_ws;
  uint8_t* x1 = ws8 + 32768;            // [8,32,255,256B] nibbles: 16,711,680 B
  uint8_t* x2 = x1 + 16711680;          // [8,32,128,256]:  8,388,608 B
  uint8_t* x3 = x2 + 8388608;           // [8,48,128,256]: 12,582,912 B
  uint8_t* x4 = ws8 + 32768;            // [8,48,64,128]: aliases x1 (dead)

  prep_all<<<224, 64, 0, stream>>>(w1, g1, b1, m1, v1,
                                   wdw1, g2, b2, m2, v2,
                                   wpw1, g3, b3, m3, v3,
                                   wdw2, g4, b4, m4, v4,
                                   wpw2, g5, b5, m5, v5, P);

  // Stage 1: 8*255*256 threads, 2 px -> 1 nibble-packed byte each
  stage1_kernel<<<2040, 256, 0, stream>>>(x, P, s1, x1);
  // dw1: 32ch, 255x511 px (256B/row nibble-packed) -> 128x256 byte codes
  dw_kernel<32, 255, 511, 256, 128, 256, true>
      <<<8192, 256, 0, stream>>>(x1, wq2, inv2, beta2, s1, s2, x2);
  // pw1: 32->48 @128x256, single chunk, 1 px/thread, rotated prefetch
  pw_kernel<32, 48, 48, 32768, false, true>
      <<<1024, 256, 0, stream>>>(x2, wq3, inv3, beta3, s2, s3, x3);
  // dw2: 48ch, 128x256 -> 64x128 (byte codes)
  dw_kernel<48, 128, 256, 256, 64, 128, false>
      <<<3072, 256, 0, stream>>>(x3, wq4, inv4, beta4, s3, s4, x4);
  // pw2: 48->64 @64x128 -> fp32, chunk 16 (4 chunks), 1 px/thread
  pw_kernel<48, 64, 16, 8192, true, false>
      <<<1024, 256, 0, stream>>>(x4, wq5, inv5, beta5, s4, s5, (float*)d_out);
}